// Round 8
// baseline (118.989 us; speedup 1.0000x reference)
//
#include <hip/hip_runtime.h>
#include <hip/hip_bf16.h>

#define N_TOK  1728     // 12*12*12
#define CDIM   64
#define NHEADS 32       // head_dim = 2
#define QTILES 27       // 1728 / 64
#define NPAIR  (N_TOK / 2)             // 864 key pairs
#define SCALE  0.70710678118654752f    // 1/sqrt(2)
#define LOG2E  1.44269504088896340736f
#define JW     8                       // waves per attn block (j-split)
#define PCHUNK (NPAIR / JW)            // 108 key pairs per wave

typedef float v2f __attribute__((ext_vector_type(2)));
static __device__ __forceinline__ v2f mk2(float a, float b) {
    v2f r; r.x = a; r.y = b; return r;
}

// ---- dtype-adaptive load: f32=1 -> fp32 buffer, 0 -> bf16 buffer ----
__device__ __forceinline__ float ldin(const void* p, int i, int f32) {
    if (f32) return ((const float*)p)[i];
    union { unsigned int b; float f; } c;
    c.b = ((unsigned int)((const unsigned short*)p)[i]) << 16;
    return c.f;
}

// ---- wave-local dtype sniff: fp32 bits read as bf16 show exp=0xFF / huge ----
__device__ __forceinline__ int sniff_f32(const void* x) {
    union { unsigned int b; float f; } c;
    c.b = ((unsigned int)((const unsigned short*)x)[threadIdx.x & 63]) << 16;
    int bad = (((c.b >> 23) & 0xFF) == 0xFF) || (fabsf(c.f) > 1e10f);
    return (__ballot(bad) != 0ULL) ? 1 : 0;
}

// ========== Kernel 1: fused QKV + attention ==========
// grid 864 = 32 heads x 27 q-tiles, block 512 (8 waves).
// Block recomputes its head's K/V for ALL tokens into LDS in a
// pair-transposed layout: Kp[p]=(k0a,k0b,k1a,k1b), Vp[p]=(v0a,v0b,v1a,v1b)
// so the attention inner loop runs on 2-wide vectors (v_pk_fma_f32 eligible).
__global__ void __launch_bounds__(512, 4)
attn_fused(const void* __restrict__ x, const void* __restrict__ w_qkv,
           __hip_bfloat16* __restrict__ Ob) {
    __shared__ float4 Kp[NPAIR];           // 13824 B
    __shared__ float4 Vp[NPAIR];           // 13824 B
    __shared__ float4 Wkv[CDIM];           //  1024 B (wk0,wk1,wv0,wv1) per c
    __shared__ float2 Wq[CDIM];            //   512 B
    __shared__ float2 Qs[64];              //   512 B pre-scaled queries
    __shared__ float  redbuf[JW * 64 * 3]; //  6144 B
    const int f    = sniff_f32(x);
    const int tid  = threadIdx.x;
    const int lane = tid & 63;
    const int wav  = tid >> 6;
    const int h    = blockIdx.x / QTILES;
    const int t0   = (blockIdx.x % QTILES) * 64;

    // stage weights: 384 elements, one per thread
    for (int e = tid; e < 6 * CDIM; e += 512) {
        int r = e >> 6, c = e & 63;
        int row = ((r >> 1) << 6) + 2 * h + (r & 1);  // q:0-63,k:64-127,v:128-191
        float w = ldin(w_qkv, row * CDIM + c, f);
        if (r < 2) ((float*)&Wq[c])[r]      = w;
        else       ((float*)&Wkv[c])[r - 2] = w;
    }
    __syncthreads();

    // stage KV (+Q for this block's 64 queries); 1 ds_read_b128/c for weights
    for (int it = 0; it < 4; ++it) {
        int n = it * 512 + tid;
        if (n < N_TOK) {                       // wave-uniform (1728 = 27 waves)
            v2f kk = mk2(0.f, 0.f), vv = mk2(0.f, 0.f);
            if ((n & ~63) == t0) {             // wave-uniform: also Q
                v2f qq = mk2(0.f, 0.f);
#pragma unroll 8
                for (int c = 0; c < CDIM; ++c) {
                    float4 w  = Wkv[c];
                    float2 wq = Wq[c];
                    float xv  = ldin(x, c * N_TOK + n, f);
                    v2f   xs  = mk2(xv, xv);
                    qq += xs * mk2(wq.x, wq.y);
                    kk += xs * mk2(w.x, w.y);
                    vv += xs * mk2(w.z, w.w);
                }
                Qs[n - t0] = make_float2(qq.x * (SCALE * LOG2E),
                                         qq.y * (SCALE * LOG2E));
            } else {
#pragma unroll 8
                for (int c = 0; c < CDIM; ++c) {
                    float4 w = Wkv[c];
                    float xv = ldin(x, c * N_TOK + n, f);
                    v2f   xs = mk2(xv, xv);
                    kk += xs * mk2(w.x, w.y);
                    vv += xs * mk2(w.z, w.w);
                }
            }
            int p = n >> 1, o = n & 1;         // pair-transposed scatter (b32 x4)
            float* kw = (float*)&Kp[p];
            float* vw = (float*)&Vp[p];
            kw[o] = kk.x; kw[2 + o] = kk.y;
            vw[o] = vv.x; vw[2 + o] = vv.y;
        }
    }
    __syncthreads();

    // attention: wave streams its 108 key-pairs; reg double-buffer, dual acc.
    float2 qf = Qs[lane];
    v2f qx = mk2(qf.x, qf.x), qy = mk2(qf.y, qf.y);
    const float4* Kw = &Kp[wav * PCHUNK];
    const float4* Vw = &Vp[wav * PCHUNK];
    float4 kc0 = Kw[0], vc0 = Vw[0], kc1 = Kw[1], vc1 = Vw[1];
    v2f l0 = mk2(0,0), l1 = mk2(0,0), a0 = mk2(0,0), a1 = mk2(0,0),
        b0 = mk2(0,0), b1 = mk2(0,0);
    for (int i = 0; i < PCHUNK; i += 2) {
        int nx = (i + 2 < PCHUNK) ? i + 2 : i;     // clamped prefetch index
        float4 kn0 = Kw[nx], vn0 = Vw[nx], kn1 = Kw[nx + 1], vn1 = Vw[nx + 1];
        // pair A: scores for keys (2i, 2i+1) as packed fp32
        v2f s0 = qx * mk2(kc0.x, kc0.y) + qy * mk2(kc0.z, kc0.w);
        v2f e0 = mk2(__builtin_amdgcn_exp2f(s0.x), __builtin_amdgcn_exp2f(s0.y));
        l0 += e0; a0 += e0 * mk2(vc0.x, vc0.y); b0 += e0 * mk2(vc0.z, vc0.w);
        // pair B
        v2f s1 = qx * mk2(kc1.x, kc1.y) + qy * mk2(kc1.z, kc1.w);
        v2f e1 = mk2(__builtin_amdgcn_exp2f(s1.x), __builtin_amdgcn_exp2f(s1.y));
        l1 += e1; a1 += e1 * mk2(vc1.x, vc1.y); b1 += e1 * mk2(vc1.z, vc1.w);
        kc0 = kn0; vc0 = vn0; kc1 = kn1; vc1 = vn1;
    }
    float* red = redbuf + wav * 192 + lane * 3;    // stride-3: <=2-way (free)
    red[0] = l0.x + l0.y + l1.x + l1.y;
    red[1] = a0.x + a0.y + a1.x + a1.y;
    red[2] = b0.x + b0.y + b1.x + b1.y;
    __syncthreads();
    if (wav == 0) {
        float L = 0.f, A = 0.f, B = 0.f;
#pragma unroll
        for (int w = 0; w < JW; ++w) {
            const float* r = redbuf + w * 192 + lane * 3;
            L += r[0]; A += r[1]; B += r[2];
        }
        float inv = 1.0f / L;
        __hip_bfloat162 o;
        o.x = __float2bfloat16(A * inv);
        o.y = __float2bfloat16(B * inv);
        int n = t0 + lane;
        *((__hip_bfloat162*)(Ob + n * CDIM + 2 * h)) = o;  // 4B-aligned
    }
}

// ========== Kernel 2: output projection (unchanged from R7, proven) ==========
__global__ void __launch_bounds__(256)
proj_kernel(const void* __restrict__ x,   // dtype sniff only
            const __hip_bfloat16* __restrict__ Ob,
            const void* __restrict__ w_proj, const void* __restrict__ b_proj,
            void* __restrict__ out) {
    __shared__ float Ws[CDIM * 65];        // transposed w_proj, padded
    const int f    = sniff_f32(x);
    const int tid  = threadIdx.x;
    const int lane = tid & 63;
    const int wav  = tid >> 6;
    for (int e = tid; e < CDIM * CDIM; e += 256)    // e = co*64+ci, coalesced
        Ws[(e & 63) * 65 + (e >> 6)] = ldin(w_proj, e, f);
    __syncthreads();
    int n = blockIdx.x * 4 + wav;          // 432*4 = 1728
    float acc = ldin(b_proj, lane, f);
#pragma unroll 8
    for (int ci = 0; ci < CDIM; ++ci)
        acc = fmaf(ldin(Ob, n * CDIM + ci, 0),       // uniform row: broadcast
                   Ws[ci * 65 + lane], acc);          // conflict-free
    if (f) ((float*)out)[n * CDIM + lane] = acc;
    else   ((__hip_bfloat16*)out)[n * CDIM + lane] = __float2bfloat16(acc);
}

extern "C" void kernel_launch(void* const* d_in, const int* in_sizes, int n_in,
                              void* d_out, int out_size, void* d_ws, size_t ws_size,
                              hipStream_t stream) {
    const void* x      = d_in[0];
    const void* w_qkv  = d_in[1];
    const void* w_proj = d_in[2];
    const void* b_proj = d_in[3];

    __hip_bfloat16* Ob = (__hip_bfloat16*)d_ws;   // [1728][64] bf16, 221184 B

    attn_fused <<<NHEADS * QTILES, 512, 0, stream>>>(x, w_qkv, Ob);
    proj_kernel<<<432, 256, 0, stream>>>(x, Ob, w_proj, b_proj, d_out);
}

// Round 9
// 104.624 us; speedup vs baseline: 1.1373x; 1.1373x over previous
//
#include <hip/hip_runtime.h>
#include <hip/hip_bf16.h>

#define N_TOK  1728     // 12*12*12
#define CDIM   64
#define NHEADS 32       // head_dim = 2
#define QTILES 27       // 1728 / 64
#define SCALE  0.70710678118654752f    // 1/sqrt(2)
#define LOG2E  1.44269504088896340736f
#define JW     8                       // waves per attn block (j-split)
#define JCHUNK (N_TOK / JW)            // 216 keys per wave

// ---- dtype-adaptive load: f32=1 -> fp32 buffer, 0 -> bf16 buffer ----
__device__ __forceinline__ float ldin(const void* p, int i, int f32) {
    if (f32) return ((const float*)p)[i];
    union { unsigned int b; float f; } c;
    c.b = ((unsigned int)((const unsigned short*)p)[i]) << 16;
    return c.f;
}

// ---- wave-local dtype sniff: fp32 bits read as bf16 show exp=0xFF / huge ----
__device__ __forceinline__ int sniff_f32(const void* x) {
    union { unsigned int b; float f; } c;
    c.b = ((unsigned int)((const unsigned short*)x)[threadIdx.x & 63]) << 16;
    int bad = (((c.b >> 23) & 0xFF) == 0xFF) || (fabsf(c.f) > 1e10f);
    return (__ballot(bad) != 0ULL) ? 1 : 0;
}

// ========== Kernel 1: fused QKV + attention ==========
// grid 864 = 32 heads x 27 q-tiles, block 512 (8 waves).
// Staging: thread t computes K/V (and Q if in-tile) for tokens 4t..4t+3 via
// one float4 x-load per channel; weights come from global with wave-uniform
// indices -> s_load_dwordx4 on the scalar pipe (zero vector-issue cost).
// KVs stored swizzled (token 4t+j at LDS index j*432+t) so b128 writes are
// lane-stride-16B (R7-proven conflict-free); attention streams linearly
// (key order permuted — l/oa/ob sums are order-invariant).
__global__ void __launch_bounds__(512, 4)
attn_fused(const void* __restrict__ xv, const void* __restrict__ wv,
           float* __restrict__ O) {
    __shared__ float4 KVs[N_TOK];          // 27648 B  {k0,k1,v0,v1}
    __shared__ float2 Qs[64];              //   512 B  pre-scaled queries
    __shared__ float  redbuf[JW * 64 * 3]; //  6144 B
    const int f    = sniff_f32(xv);
    const int tid  = threadIdx.x;
    const int lane = tid & 63;
    const int wav  = tid >> 6;
    const int h    = blockIdx.x / QTILES;
    const int t0   = (blockIdx.x % QTILES) * 64;

    if (f) {  // ---- fp32 fast staging (runtime-proven path) ----
        if (tid < 432) {
            const float* x   = (const float*)xv;
            const float* w   = (const float*)wv;
            const float* wq0 = w + (2 * h) * CDIM;       // uniform rows ->
            const float* wq1 = w + (2 * h + 1) * CDIM;   // scalar loads
            const float* wk0 = w + (64 + 2 * h) * CDIM;
            const float* wk1 = w + (65 + 2 * h) * CDIM;
            const float* wv0 = w + (128 + 2 * h) * CDIM;
            const float* wv1 = w + (129 + 2 * h) * CDIM;
            const int n0 = tid * 4;                      // tokens n0..n0+3
            const bool qd = (n0 & ~63) == t0;            // 16 threads/block
            float k0[4] = {0,0,0,0}, k1[4] = {0,0,0,0};
            float v0[4] = {0,0,0,0}, v1[4] = {0,0,0,0};
            float q0[4] = {0,0,0,0}, q1[4] = {0,0,0,0};
            if (qd) {
#pragma unroll 4
                for (int c = 0; c < CDIM; ++c) {
                    const float4 xc = *(const float4*)(x + c * N_TOK + n0);
                    const float sk0 = wk0[c], sk1 = wk1[c];
                    const float sv0 = wv0[c], sv1 = wv1[c];
                    const float sq0 = wq0[c], sq1 = wq1[c];
                    const float xs[4] = {xc.x, xc.y, xc.z, xc.w};
#pragma unroll
                    for (int j = 0; j < 4; ++j) {
                        k0[j] = fmaf(xs[j], sk0, k0[j]);
                        k1[j] = fmaf(xs[j], sk1, k1[j]);
                        v0[j] = fmaf(xs[j], sv0, v0[j]);
                        v1[j] = fmaf(xs[j], sv1, v1[j]);
                        q0[j] = fmaf(xs[j], sq0, q0[j]);
                        q1[j] = fmaf(xs[j], sq1, q1[j]);
                    }
                }
            } else {
#pragma unroll 4
                for (int c = 0; c < CDIM; ++c) {
                    const float4 xc = *(const float4*)(x + c * N_TOK + n0);
                    const float sk0 = wk0[c], sk1 = wk1[c];
                    const float sv0 = wv0[c], sv1 = wv1[c];
                    const float xs[4] = {xc.x, xc.y, xc.z, xc.w};
#pragma unroll
                    for (int j = 0; j < 4; ++j) {
                        k0[j] = fmaf(xs[j], sk0, k0[j]);
                        k1[j] = fmaf(xs[j], sk1, k1[j]);
                        v0[j] = fmaf(xs[j], sv0, v0[j]);
                        v1[j] = fmaf(xs[j], sv1, v1[j]);
                    }
                }
            }
#pragma unroll
            for (int j = 0; j < 4; ++j) {
                KVs[j * 432 + tid] = make_float4(k0[j], k1[j], v0[j], v1[j]);
                if (qd) Qs[n0 + j - t0] = make_float2(q0[j] * (SCALE * LOG2E),
                                                      q1[j] * (SCALE * LOG2E));
            }
        }
    } else {  // ---- generic bf16 fallback (never observed at runtime) ----
        for (int n = tid; n < N_TOK; n += 512) {
            float k0 = 0, k1 = 0, v0 = 0, v1 = 0, q0 = 0, q1 = 0;
            for (int c = 0; c < CDIM; ++c) {
                float xc = ldin(xv, c * N_TOK + n, 0);
                q0 = fmaf(xc, ldin(wv, (2 * h) * CDIM + c, 0), q0);
                q1 = fmaf(xc, ldin(wv, (2 * h + 1) * CDIM + c, 0), q1);
                k0 = fmaf(xc, ldin(wv, (64 + 2 * h) * CDIM + c, 0), k0);
                k1 = fmaf(xc, ldin(wv, (65 + 2 * h) * CDIM + c, 0), k1);
                v0 = fmaf(xc, ldin(wv, (128 + 2 * h) * CDIM + c, 0), v0);
                v1 = fmaf(xc, ldin(wv, (129 + 2 * h) * CDIM + c, 0), v1);
            }
            KVs[(n & 3) * 432 + (n >> 2)] = make_float4(k0, k1, v0, v1);
            if ((n & ~63) == t0)
                Qs[n - t0] = make_float2(q0 * (SCALE * LOG2E),
                                         q1 * (SCALE * LOG2E));
        }
    }
    __syncthreads();

    // ---- attention: wave streams 216 (permuted) keys, 8-deep batches ----
    const float2 q = Qs[lane];
    const float4* KVp = &KVs[wav * JCHUNK];
    float la = 0.f, lb = 0.f, oa0 = 0.f, oa1 = 0.f, ob0 = 0.f, ob1 = 0.f;
    for (int g = 0; g < JCHUNK; g += 8) {   // 27 groups of 8 keys
        float4 k[8];
#pragma unroll
        for (int u = 0; u < 8; ++u) k[u] = KVp[g + u];   // 8 reads in flight
#pragma unroll
        for (int u = 0; u < 8; ++u) {
            float e = __builtin_amdgcn_exp2f(fmaf(q.x, k[u].x, q.y * k[u].y));
            if (u & 1) { lb += e; ob0 = fmaf(e, k[u].z, ob0); ob1 = fmaf(e, k[u].w, ob1); }
            else       { la += e; oa0 = fmaf(e, k[u].z, oa0); oa1 = fmaf(e, k[u].w, oa1); }
        }
    }
    float* red = redbuf + wav * 192 + lane * 3;   // stride-3: <=2-way (free)
    red[0] = la + lb; red[1] = oa0 + ob0; red[2] = oa1 + ob1;
    __syncthreads();
    if (wav == 0) {
        float L = 0.f, A = 0.f, B = 0.f;
#pragma unroll
        for (int w = 0; w < JW; ++w) {
            const float* r = redbuf + w * 192 + lane * 3;
            L += r[0]; A += r[1]; B += r[2];
        }
        float inv = 1.0f / L;
        int n = t0 + lane;
        *((float2*)(O + n * CDIM + 2 * h)) = make_float2(A * inv, B * inv);
    }
}

// ========== Kernel 2: output projection ==========
// grid 432, block 256 (4 waves = 4 tokens). w_proj transposed into padded
// LDS [64][65]; O rows are wave-uniform fp32 -> scalar dwordx8 loads.
__global__ void __launch_bounds__(256)
proj_kernel(const void* __restrict__ xv,   // dtype sniff only
            const float* __restrict__ O,
            const void* __restrict__ w_proj, const void* __restrict__ b_proj,
            void* __restrict__ out) {
    __shared__ float Ws[CDIM * 65];        // 16640 B
    const int f    = sniff_f32(xv);
    const int tid  = threadIdx.x;
    const int lane = tid & 63;
    const int wav  = tid >> 6;
    for (int e = tid; e < CDIM * CDIM; e += 256)    // e = co*64+ci, coalesced
        Ws[(e & 63) * 65 + (e >> 6)] = ldin(w_proj, e, f);
    __syncthreads();
    int n = blockIdx.x * 4 + wav;          // 432*4 = 1728
    float acc = ldin(b_proj, lane, f);
#pragma unroll 8
    for (int ci = 0; ci < CDIM; ++ci)
        acc = fmaf(O[n * CDIM + ci],                 // uniform -> s_load
                   Ws[ci * 65 + lane], acc);          // bank-conflict-free
    if (f) ((float*)out)[n * CDIM + lane] = acc;
    else   ((__hip_bfloat16*)out)[n * CDIM + lane] = __float2bfloat16(acc);
}

extern "C" void kernel_launch(void* const* d_in, const int* in_sizes, int n_in,
                              void* d_out, int out_size, void* d_ws, size_t ws_size,
                              hipStream_t stream) {
    const void* x      = d_in[0];
    const void* w_qkv  = d_in[1];
    const void* w_proj = d_in[2];
    const void* b_proj = d_in[3];

    float* O = (float*)d_ws;   // [1728][64] fp32, 442368 B (ws >= 1.77 MB proven)

    attn_fused <<<NHEADS * QTILES, 512, 0, stream>>>(x, w_qkv, O);
    proj_kernel<<<432, 256, 0, stream>>>(x, O, w_proj, b_proj, d_out);
}